// Round 4
// baseline (161.657 us; speedup 1.0000x reference)
//
#include <hip/hip_runtime.h>
#include <stdint.h>

#define NN 4096
#define MM 8192
#define DD 512
#define KT 8  // 512 / BK, BK = 64

typedef __bf16 bf16x8 __attribute__((ext_vector_type(8)));
typedef __bf16 bf16x4 __attribute__((ext_vector_type(4)));
typedef float f32x4 __attribute__((ext_vector_type(4)));
typedef float f32x16 __attribute__((ext_vector_type(16)));

__device__ __forceinline__ void load_lds16(const void* g, void* l) {
  // async global -> LDS, 16B/lane; LDS dest must be wave-uniform base + lane*16.
  __builtin_amdgcn_global_load_lds(
      (const __attribute__((address_space(1))) unsigned int*)g,
      (__attribute__((address_space(3))) unsigned int*)l, 16, 0, 0);
}

// VALU-pipe partial reduction (R7/R8-verified correct): x += rot16(x, k).
template <int CTRL>
__device__ __forceinline__ float dpp_radd(float x) {
  int xi = __float_as_int(x);
  int mv = __builtin_amdgcn_update_dpp(xi, xi, CTRL, 0xF, 0xF, false);
  return x + __int_as_float(mv);
}
__device__ __forceinline__ float swz_add_xor16(float x) {
  int sv = __builtin_amdgcn_ds_swizzle(__float_as_int(x), 0x401F);
  return x + __int_as_float(sv);
}

// 4 rows per 256-thread block, one wave per row. Fully-coalesced f32x4 loads,
// bf16x4 stores, exact fp32 row-norm, and out[]=IC init folded in.
__global__ __launch_bounds__(256) void convert_norm_kernel(
    const float* __restrict__ X, const float* __restrict__ SV,
    __bf16* __restrict__ Xb, __bf16* __restrict__ SVb,
    float* __restrict__ x2, float* __restrict__ sv2,
    float* __restrict__ out, const float* __restrict__ IC) {
  int wid = blockIdx.x * 4 + (threadIdx.x >> 6);
  int lane = threadIdx.x & 63;
  const float* src;
  __bf16* dst;
  float* nrm;
  if (wid < NN) {
    src = X + (size_t)wid * DD;
    dst = Xb + (size_t)wid * DD;
    nrm = x2 + wid;
    if (lane == 0) out[wid] = IC[0];
  } else {
    int r = wid - NN;
    src = SV + (size_t)r * DD;
    dst = SVb + (size_t)r * DD;
    nrm = sv2 + r;
  }
  const f32x4* s = (const f32x4*)src;
  f32x4 a = s[lane];       // elements 4l..4l+3
  f32x4 b = s[lane + 64];  // elements 256+4l..
  float sum = a.x * a.x + a.y * a.y + a.z * a.z + a.w * a.w +
              b.x * b.x + b.y * b.y + b.z * b.z + b.w * b.w;
  bf16x4 ca = {(__bf16)a.x, (__bf16)a.y, (__bf16)a.z, (__bf16)a.w};
  bf16x4 cb = {(__bf16)b.x, (__bf16)b.y, (__bf16)b.z, (__bf16)b.w};
  *(bf16x4*)(dst + 4 * lane) = ca;
  *(bf16x4*)(dst + 256 + 4 * lane) = cb;
#pragma unroll
  for (int m = 32; m >= 1; m >>= 1) sum += __shfl_xor(sum, m, 64);
  if (lane == 0) *nrm = sum;
}

// R3 structure (128x128, BK=64, 4 waves 2x2, XCD-chunked swizzle) with ONE
// change: B (SVb) no longer goes through LDS. Each lane loads its B fragment
// directly from global (L1/L2-hot: 32B/row-line per ks, full 128B line
// consumed across the kt; per-wave working set 8KB). Algebra check: LDS
// round-trip stored granule kc^(row&7) at slot and read it back at
// kc^(l31&7) with row==l31 (mod rows) -> direct granule index is just
// kt*8 + ks*2 + lhi. This halves LDS reads + conflicts and halves staging
// writes, rebalancing the one 128B/cyc LDS pipe (measured critical at ~52%
// of cycles) against the idle vmem/L2 path. A path byte-identical to R3.
__global__ __launch_bounds__(256, 4) void rbf_gemm_kernel(
    const bf16x8* __restrict__ Xb, const bf16x8* __restrict__ SVb,
    const float* __restrict__ x2, const float* __restrict__ sv2,
    const float* __restrict__ DC, const float* __restrict__ gamma_p,
    float* __restrict__ out) {
  __shared__ bf16x8 As[1024];  // 16 KB (A only)

  const int t = threadIdx.x;
  const int lane = t & 63;
  const int wave = t >> 6;

  // ---- XCD-chunked bijective swizzle (R3-verified: FETCH 35->16.6 MB) ----
  const int id = blockIdx.y * gridDim.x + blockIdx.x;
  const int xcd = id & 7;
  const int idx = id >> 3;
  const int bn = (xcd & 1) * 16 + (idx & 15);
  const int bm = (xcd >> 1) * 16 + (idx >> 4);
  const int n0 = bn * 128;
  const int m0 = bm * 128;

  const int wave_m = wave & 1;   // m-dir of C
  const int wave_n = wave >> 1;  // n-dir of C
  const int l31 = lane & 31;
  const int lhi = lane >> 5;

  // staging decomposition (A only): chunk c_it = it*256 + t
  const int srow = t >> 3;  // row contribution for it=0 (rows 0..31)
  const int sslot = t & 7;

  // B direct-load bases: rows (m-cols) wave_m*64 + l31 and +32.
  const bf16x8* pb0 = SVb + (size_t)(m0 + wave_m * 64 + l31) * 64;
  const bf16x8* pb1 = pb0 + 32 * 64;

  f32x16 acc[2][2];
#pragma unroll
  for (int i = 0; i < 2; ++i)
#pragma unroll
    for (int j = 0; j < 2; ++j)
#pragma unroll
      for (int r = 0; r < 16; ++r) acc[i][j][r] = 0.0f;

  for (int kt = 0; kt < KT; ++kt) {
    // ---- cooperative A staging: 4 instrs per thread ----
#pragma unroll
    for (int it = 0; it < 4; ++it) {
      const int c = it * 256 + t;
      const int row = it * 32 + srow;
      const int kg = sslot ^ (row & 7);
      load_lds16(Xb + (size_t)(n0 + row) * 64 + kt * 8 + kg, &As[c]);
    }
    // ---- B fragments direct from global (latency hidden by the sync's
    // drain of the A staging; all 8 independent) ----
    bf16x8 bq[4][2];
#pragma unroll
    for (int ks = 0; ks < 4; ++ks) {
      bq[ks][0] = pb0[kt * 8 + ks * 2 + lhi];
      bq[ks][1] = pb1[kt * 8 + ks * 2 + lhi];
    }
    __syncthreads();
    // ---- compute ----
    const int ra = (wave_n * 64 + l31) * 8;
#pragma unroll
    for (int ks = 0; ks < 4; ++ks) {
      const int kc = ks * 2 + lhi;  // k-chunk 0..7
      const int sw = kc ^ (l31 & 7);
      bf16x8 af0 = As[ra + sw];
      bf16x8 af1 = As[ra + 256 + sw];  // +32 rows
      acc[0][0] = __builtin_amdgcn_mfma_f32_32x32x16_bf16(af0, bq[ks][0], acc[0][0], 0, 0, 0);
      acc[0][1] = __builtin_amdgcn_mfma_f32_32x32x16_bf16(af0, bq[ks][1], acc[0][1], 0, 0, 0);
      acc[1][0] = __builtin_amdgcn_mfma_f32_32x32x16_bf16(af1, bq[ks][0], acc[1][0], 0, 0, 0);
      acc[1][1] = __builtin_amdgcn_mfma_f32_32x32x16_bf16(af1, bq[ks][1], acc[1][1], 0, 0, 0);
    }
    __syncthreads();
  }

  // ---- epilogue (byte-identical to R3-verified version) ----
  const float g = gamma_p[0];
  const float c2 = g * 1.4426950408889634f;  // gamma * log2(e)

  float sv2v[2], dcv[2];
  const int colb = m0 + wave_m * 64 + l31;
  sv2v[0] = sv2[colb];
  dcv[0] = DC[colb];
  sv2v[1] = sv2[colb + 32];
  dcv[1] = DC[colb + 32];

#pragma unroll
  for (int i = 0; i < 2; ++i) {
    // C row = rowb + 8*g4 + r2, where reg = g4*4 + r2
    const int rowb = n0 + wave_n * 64 + i * 32 + 4 * lhi;
    float val[16];
#pragma unroll
    for (int g4 = 0; g4 < 4; ++g4) {
      f32x4 xv = *(const f32x4*)(x2 + rowb + 8 * g4);
#pragma unroll
      for (int r2 = 0; r2 < 4; ++r2) {
        const int reg = g4 * 4 + r2;
        float v = 0.0f;
#pragma unroll
        for (int j = 0; j < 2; ++j) {
          float d2 = xv[r2] + sv2v[j] - 2.0f * acc[i][j][reg];
          d2 = fmaxf(d2, 0.0f);
          v += exp2f(-c2 * d2) * dcv[j];
        }
        val[reg] = v;
      }
    }
    // reduce over 32 column-lanes: 4 DPP row-rotations (VALU pipe) + one
    // ds_swizzle xor16 (R7/R8-verified).
#pragma unroll
    for (int reg = 0; reg < 16; ++reg) {
      float v = val[reg];
      v = dpp_radd<0x121>(v);  // row_ror:1
      v = dpp_radd<0x122>(v);  // row_ror:2
      v = dpp_radd<0x124>(v);  // row_ror:4
      v = dpp_radd<0x128>(v);  // row_ror:8
      val[reg] = swz_add_xor16(v);
    }
    if (l31 == 0) {
#pragma unroll
      for (int g4 = 0; g4 < 4; ++g4)
#pragma unroll
        for (int r2 = 0; r2 < 4; ++r2)
          atomicAdd(&out[rowb + 8 * g4 + r2], val[g4 * 4 + r2]);
    }
  }
}

extern "C" void kernel_launch(void* const* d_in, const int* in_sizes, int n_in,
                              void* d_out, int out_size, void* d_ws, size_t ws_size,
                              hipStream_t stream) {
  const float* X = (const float*)d_in[0];
  const float* SV = (const float*)d_in[1];
  const float* DC = (const float*)d_in[2];
  const float* IC = (const float*)d_in[3];
  const float* gamma = (const float*)d_in[4];
  float* out = (float*)d_out;

  char* ws = (char*)d_ws;
  __bf16* Xb = (__bf16*)ws;                                   // 4 MB
  __bf16* SVb = (__bf16*)(ws + (size_t)NN * DD * 2);          // 8 MB
  float* x2 = (float*)(ws + (size_t)(NN + MM) * DD * 2);      // 16 KB
  float* sv2 = x2 + NN;                                       // 32 KB

  convert_norm_kernel<<<(NN + MM) / 4, 256, 0, stream>>>(X, SV, Xb, SVb, x2, sv2, out, IC);
  dim3 grid(NN / 128, MM / 128);
  rbf_gemm_kernel<<<grid, 256, 0, stream>>>((const bf16x8*)Xb, (const bf16x8*)SVb,
                                            x2, sv2, DC, gamma, out);
}

// Round 5
// 139.687 us; speedup vs baseline: 1.1573x; 1.1573x over previous
//
#include <hip/hip_runtime.h>
#include <stdint.h>

#define NN 4096
#define MM 8192
#define DD 512
#define KT 8  // 512 / BK, BK = 64

typedef __bf16 bf16x8 __attribute__((ext_vector_type(8)));
typedef __bf16 bf16x4 __attribute__((ext_vector_type(4)));
typedef float f32x4 __attribute__((ext_vector_type(4)));
typedef float f32x16 __attribute__((ext_vector_type(16)));

__device__ __forceinline__ void load_lds16(const void* g, void* l) {
  // async global -> LDS, 16B/lane; LDS dest must be wave-uniform base + lane*16.
  __builtin_amdgcn_global_load_lds(
      (const __attribute__((address_space(1))) unsigned int*)g,
      (__attribute__((address_space(3))) unsigned int*)l, 16, 0, 0);
}

// VALU-pipe partial reduction (R7/R8-verified correct): x += rot16(x, k).
template <int CTRL>
__device__ __forceinline__ float dpp_radd(float x) {
  int xi = __float_as_int(x);
  int mv = __builtin_amdgcn_update_dpp(xi, xi, CTRL, 0xF, 0xF, false);
  return x + __int_as_float(mv);
}
__device__ __forceinline__ float swz_add_xor16(float x) {
  int sv = __builtin_amdgcn_ds_swizzle(__float_as_int(x), 0x401F);
  return x + __int_as_float(sv);
}

// Blocks 0..1023: X rows (4/block, previous verified path, out[]=IC init).
// Blocks 1024..1279: SV rows, 32/block, written TRANSPOSED to fragment-major
// tiles SVbT[m/32][g][m&31] (16B granules, g = k-granule 0..63) via an
// LDS transpose (XOR-swizzled slots, coalesced global in AND out), so the
// GEMM can read B fragments directly from global as contiguous 1024B/wave.
__global__ __launch_bounds__(256) void convert_norm_kernel(
    const float* __restrict__ X, const float* __restrict__ SV,
    __bf16* __restrict__ Xb, bf16x8* __restrict__ SVbT,
    float* __restrict__ x2, float* __restrict__ sv2,
    float* __restrict__ out, const float* __restrict__ IC) {
  __shared__ bf16x8 T[2048];  // 32 KB [32 rows][64 swizzled slots]
  const int b = blockIdx.x;
  const int t = threadIdx.x;
  if (b < NN / 4) {
    // ---- X part: 4 rows per block, one wave per row (verified path) ----
    int wid = b * 4 + (t >> 6);
    int lane = t & 63;
    const float* src = X + (size_t)wid * DD;
    __bf16* dst = Xb + (size_t)wid * DD;
    if (lane == 0) out[wid] = IC[0];
    const f32x4* s = (const f32x4*)src;
    f32x4 a = s[lane];       // elements 4l..4l+3
    f32x4 c = s[lane + 64];  // elements 256+4l..
    float sum = a.x * a.x + a.y * a.y + a.z * a.z + a.w * a.w +
                c.x * c.x + c.y * c.y + c.z * c.z + c.w * c.w;
    bf16x4 ca = {(__bf16)a.x, (__bf16)a.y, (__bf16)a.z, (__bf16)a.w};
    bf16x4 cb = {(__bf16)c.x, (__bf16)c.y, (__bf16)c.z, (__bf16)c.w};
    *(bf16x4*)(dst + 4 * lane) = ca;
    *(bf16x4*)(dst + 256 + 4 * lane) = cb;
#pragma unroll
    for (int m = 32; m >= 1; m >>= 1) sum += __shfl_xor(sum, m, 64);
    if (lane == 0) x2[wid] = sum;
  } else {
    // ---- SV part: 32 rows per block, transposed output ----
    const int mb = b - NN / 4;  // 0..255
    const int mbase = mb * 32;
    const int r = t >> 3;   // row-within-block 0..31 (= wave*8 + lane>>3)
    const int cq = t & 7;   // col-eighth (64 f32 each)
    const float* src = SV + (size_t)(mbase + r) * DD + cq * 64;
    const f32x4* s4 = (const f32x4*)src;
    float sum = 0.0f;
    bf16x8 gr[8];
#pragma unroll
    for (int j = 0; j < 8; ++j) {
      f32x4 a = s4[2 * j];
      f32x4 c = s4[2 * j + 1];
      sum += a.x * a.x + a.y * a.y + a.z * a.z + a.w * a.w +
             c.x * c.x + c.y * c.y + c.z * c.z + c.w * c.w;
      gr[j] = {(__bf16)a.x, (__bf16)a.y, (__bf16)a.z, (__bf16)a.w,
               (__bf16)c.x, (__bf16)c.y, (__bf16)c.z, (__bf16)c.w};
    }
    // swizzled LDS store: row r, global granule g -> slot g ^ (r&7)
#pragma unroll
    for (int j = 0; j < 8; ++j) {
      const int g = cq * 8 + j;
      T[r * 64 + (g ^ (r & 7))] = gr[j];
    }
    // row norm: 8 threads per row, all within one wave (lanes differ in bits 0..2)
    sum += __shfl_xor(sum, 1, 64);
    sum += __shfl_xor(sum, 2, 64);
    sum += __shfl_xor(sum, 4, 64);
    if (cq == 0) sv2[mbase + r] = sum;
    __syncthreads();
    // coalesced transposed write: flat granule fl = g*32 + m31
#pragma unroll
    for (int it = 0; it < 8; ++it) {
      const int fl = it * 256 + t;
      const int m31 = fl & 31;
      const int g = fl >> 5;
      SVbT[(size_t)mb * 2048 + fl] = T[m31 * 64 + (g ^ (m31 & 7))];
    }
  }
}

// R3 structure (128x128, BK=64, 4 waves 2x2, XCD-chunked swizzle) with B taken
// off the LDS pipe: B fragments load directly from the fragment-major SVbT —
// each wave-instr reads 1024B CONTIGUOUS (fixing R4's 32-line gather, which
// was the measured regression mechanism). LDS now stages A only: ds_reads
// halve (MFMA:ds = 2:1), B staging writes vanish, conflicts halve; the
// syncthreads that drains A staging covers bq latency for free. Epilogue
// thinned 5->4 VALU/value via k = exp2(min(2c2*acc - c2*xv - c2*sv2, 0))
// (exactly equivalent: min(-c2*t,0) == -c2*max(t,0) for c2>0).
__global__ __launch_bounds__(256, 4) void rbf_gemm_kernel(
    const bf16x8* __restrict__ Xb, const bf16x8* __restrict__ SVbT,
    const float* __restrict__ x2, const float* __restrict__ sv2,
    const float* __restrict__ DC, const float* __restrict__ gamma_p,
    float* __restrict__ out) {
  __shared__ bf16x8 As[1024];  // 16 KB (A only)

  const int t = threadIdx.x;
  const int lane = t & 63;
  const int wave = t >> 6;

  // ---- XCD-chunked bijective swizzle (R3-verified: FETCH 35->16.6 MB) ----
  const int id = blockIdx.y * gridDim.x + blockIdx.x;
  const int xcd = id & 7;
  const int idx = id >> 3;
  const int bn = (xcd & 1) * 16 + (idx & 15);
  const int bm = (xcd >> 1) * 16 + (idx >> 4);
  const int n0 = bn * 128;
  const int m0 = bm * 128;

  const int wave_m = wave & 1;   // m-dir of C
  const int wave_n = wave >> 1;  // n-dir of C
  const int l31 = lane & 31;
  const int lhi = lane >> 5;

  // staging decomposition (A only): chunk c_it = it*256 + t
  const int srow = t >> 3;  // row contribution for it=0 (rows 0..31)
  const int sslot = t & 7;

  // B direct-load bases: 32-row granule-blocks (m0/32 + wave_m*2) and +1.
  // flat granule = mblk*2048 + g*32 + l31  -> lanes contiguous, lhi -> g+1:
  // 64 lanes span 1024B contiguous per load.
  const int mblk = (m0 >> 5) + wave_m * 2;
  const bf16x8* pb0 = SVbT + (size_t)mblk * 2048 + l31;
  const bf16x8* pb1 = pb0 + 2048;

  f32x16 acc[2][2];
#pragma unroll
  for (int i = 0; i < 2; ++i)
#pragma unroll
    for (int j = 0; j < 2; ++j)
#pragma unroll
      for (int r = 0; r < 16; ++r) acc[i][j][r] = 0.0f;

  for (int kt = 0; kt < KT; ++kt) {
    // ---- cooperative A staging: 4 instrs per thread ----
#pragma unroll
    for (int it = 0; it < 4; ++it) {
      const int c = it * 256 + t;
      const int row = it * 32 + srow;
      const int kg = sslot ^ (row & 7);
      load_lds16(Xb + (size_t)(n0 + row) * 64 + kt * 8 + kg, &As[c]);
    }
    // ---- B fragments direct from global, 1024B contiguous per wave-instr;
    // latency hidden by the barrier's drain of the A staging ----
    bf16x8 bq[4][2];
#pragma unroll
    for (int ks = 0; ks < 4; ++ks) {
      const int gi = (kt * 8 + ks * 2 + lhi) * 32;
      bq[ks][0] = pb0[gi];
      bq[ks][1] = pb1[gi];
    }
    __syncthreads();
    // ---- compute: 8 ds_read_b128 + 16 MFMA per wave per kt ----
    const int ra = (wave_n * 64 + l31) * 8;
#pragma unroll
    for (int ks = 0; ks < 4; ++ks) {
      const int sw = (ks * 2 + lhi) ^ (l31 & 7);
      bf16x8 af0 = As[ra + sw];
      bf16x8 af1 = As[ra + 256 + sw];  // +32 rows
      acc[0][0] = __builtin_amdgcn_mfma_f32_32x32x16_bf16(af0, bq[ks][0], acc[0][0], 0, 0, 0);
      acc[0][1] = __builtin_amdgcn_mfma_f32_32x32x16_bf16(af0, bq[ks][1], acc[0][1], 0, 0, 0);
      acc[1][0] = __builtin_amdgcn_mfma_f32_32x32x16_bf16(af1, bq[ks][0], acc[1][0], 0, 0, 0);
      acc[1][1] = __builtin_amdgcn_mfma_f32_32x32x16_bf16(af1, bq[ks][1], acc[1][1], 0, 0, 0);
    }
    __syncthreads();
  }

  // ---- epilogue (structure identical to verified version; math thinned) ----
  const float g = gamma_p[0];
  const float c2 = g * 1.4426950408889634f;  // gamma * log2(e)
  const float t2 = 2.0f * c2;

  float sv2v[2], dcv[2], nsv[2];
  const int colb = m0 + wave_m * 64 + l31;
  sv2v[0] = sv2[colb];
  dcv[0] = DC[colb];
  sv2v[1] = sv2[colb + 32];
  dcv[1] = DC[colb + 32];
  nsv[0] = -c2 * sv2v[0];
  nsv[1] = -c2 * sv2v[1];

#pragma unroll
  for (int i = 0; i < 2; ++i) {
    // C row = rowb + 8*g4 + r2, where reg = g4*4 + r2
    const int rowb = n0 + wave_n * 64 + i * 32 + 4 * lhi;
    float val[16];
#pragma unroll
    for (int g4 = 0; g4 < 4; ++g4) {
      f32x4 xv = *(const f32x4*)(x2 + rowb + 8 * g4);
#pragma unroll
      for (int r2 = 0; r2 < 4; ++r2) {
        const int reg = g4 * 4 + r2;
        float v = 0.0f;
#pragma unroll
        for (int j = 0; j < 2; ++j) {
          float e = fmaf(t2, acc[i][j][reg], fmaf(-c2, xv[r2], nsv[j]));
          e = fminf(e, 0.0f);  // == -c2 * max(d2, 0)
          v = fmaf(exp2f(e), dcv[j], v);
        }
        val[reg] = v;
      }
    }
    // reduce over 32 column-lanes: 4 DPP row-rotations (VALU pipe) + one
    // ds_swizzle xor16 (R7/R8-verified).
#pragma unroll
    for (int reg = 0; reg < 16; ++reg) {
      float v = val[reg];
      v = dpp_radd<0x121>(v);  // row_ror:1
      v = dpp_radd<0x122>(v);  // row_ror:2
      v = dpp_radd<0x124>(v);  // row_ror:4
      v = dpp_radd<0x128>(v);  // row_ror:8
      val[reg] = swz_add_xor16(v);
    }
    if (l31 == 0) {
#pragma unroll
      for (int g4 = 0; g4 < 4; ++g4)
#pragma unroll
        for (int r2 = 0; r2 < 4; ++r2)
          atomicAdd(&out[rowb + 8 * g4 + r2], val[g4 * 4 + r2]);
    }
  }
}

extern "C" void kernel_launch(void* const* d_in, const int* in_sizes, int n_in,
                              void* d_out, int out_size, void* d_ws, size_t ws_size,
                              hipStream_t stream) {
  const float* X = (const float*)d_in[0];
  const float* SV = (const float*)d_in[1];
  const float* DC = (const float*)d_in[2];
  const float* IC = (const float*)d_in[3];
  const float* gamma = (const float*)d_in[4];
  float* out = (float*)d_out;

  char* ws = (char*)d_ws;
  __bf16* Xb = (__bf16*)ws;                                   // 4 MB
  bf16x8* SVbT = (bf16x8*)(ws + (size_t)NN * DD * 2);         // 8 MB
  float* x2 = (float*)(ws + (size_t)(NN + MM) * DD * 2);      // 16 KB
  float* sv2 = x2 + NN;                                       // 32 KB

  convert_norm_kernel<<<NN / 4 + MM / 32, 256, 0, stream>>>(X, SV, Xb, SVbT, x2, sv2, out, IC);
  dim3 grid(NN / 128, MM / 128);
  rbf_gemm_kernel<<<grid, 256, 0, stream>>>((const bf16x8*)Xb, SVbT,
                                            x2, sv2, DC, gamma, out);
}